// Round 5
// baseline (193.373 us; speedup 1.0000x reference)
//
#include <hip/hip_runtime.h>

typedef short bf16x8 __attribute__((ext_vector_type(8)));
typedef float f32x16 __attribute__((ext_vector_type(16)));

constexpr int S = 2048;
constexpr int H = 16;
constexpr int D = 128;
constexpr int BM = 128;    // q rows per phase (4 q-groups x 32)
constexpr int TILE = 8192; // shorts per 64-row K/V tile (16 KB)
constexpr int KSTR = 136;  // prepass staging LDS stride (shorts)
constexpr int MST = 33;    // merge scratch stride (floats): bank = lane+r, clean

// ---------------------------------------------------------------------------
// Workspace tile layouts (per (b,h), 32 tiles of 16KB, fully linear for DMA):
//  K tile: 8 groups of 2KB; group g = rows 8g..8g+7. 16B-slot within group:
//     slot(rho,c) = rho*16 + (c ^ rho), rho = row&7, c = d-chunk 0..15.
//  V tile: [d][sigma], sigma(k) = k with bits 2<->3 swapped; 16 groups of 1KB
//     (8 d-rows), slot(rho,cc) = rho*8 + (cc ^ rho).  sigma makes 8 contiguous
//     shorts a valid MFMA A-operand matching the B-operand built by packing
//     exp(S^T) regs pairwise.  P never touches LDS.
//
// fa_fwd v5: 256 blocks x 512 thr, 1 block/CU, q-pair schedule (exactly 34
// tiles/block).  Triple-buffered K/V; iter j = [vmcnt(0)+barrier (drains
// stage(j+1), issued a FULL iteration earlier) | issue stage(j+2) |
// QK(j+1) || softmax(j) || PV(j) in one barrier-free region].  T15: softmax(j)
// co-issues with QK(j+1) MFMAs.  Merge scratch aliases Kl, stride 33.
// ---------------------------------------------------------------------------

__device__ inline unsigned int pk2(float a, float b) {
    // pack 2 f32 -> 2 bf16 (RNE bit-trick; finite values only). low=a, high=b
    unsigned int ua = __builtin_bit_cast(unsigned int, a);
    unsigned int ub = __builtin_bit_cast(unsigned int, b);
    ua += 0x7fffu + ((ua >> 16) & 1u);
    ub += 0x7fffu + ((ub >> 16) & 1u);
    return (ua >> 16) | (ub & 0xffff0000u);
}

__device__ __forceinline__ void gld16(const unsigned short* g, unsigned short* l) {
    __builtin_amdgcn_global_load_lds(
        (const __attribute__((address_space(1))) unsigned int*)g,
        (__attribute__((address_space(3))) unsigned int*)l, 16, 0, 0);
}

// ---- fused prepass: K -> permuted bf16 tiles; V -> transposed+sigma tiles ----
// v2: V tile assembled in LDS (Vout) and written LINEARLY (old path scattered
// 16B granules over 4KB -> HBM write amplification).
__global__ __launch_bounds__(256) void cvt_kv(const float* __restrict__ K,
                                              const float* __restrict__ V,
                                              unsigned short* __restrict__ Kb,
                                              unsigned short* __restrict__ Vtb) {
    __shared__ unsigned short Vst[64 * KSTR];
    __shared__ unsigned short Vout[TILE];
    const int tid = threadIdx.x;
    const int t   = blockIdx.x;   // 64-row tile
    const int bh  = blockIdx.y;
    const int b = bh >> 4, h = bh & 15;
    const size_t base = ((size_t)(b * S + t * 64) * H + h) * D;

    // --- K: pack into permuted slots, contiguous dest ---
    unsigned short* outK = Kb + ((size_t)bh * 32 + t) * TILE;
    #pragma unroll
    for (int u = 0; u < 4; ++u) {
        const int dlin = u * 256 + tid;            // dest 16B-slot 0..1023
        const int grp = dlin >> 7;
        const int s   = dlin & 127;
        const int rho = s >> 4;
        const int c   = (s & 15) ^ rho;            // involution
        const float* p = K + base + (size_t)(grp * 8 + rho) * (H * D) + c * 8;
        float4 f0 = *(const float4*)p;
        float4 f1 = *(const float4*)(p + 4);
        unsigned int w[4];
        w[0] = pk2(f0.x, f0.y); w[1] = pk2(f0.z, f0.w);
        w[2] = pk2(f1.x, f1.y); w[3] = pk2(f1.z, f1.w);
        *(uint4*)(outK + dlin * 8) = *(const uint4*)w;
    }

    // --- V: stage rows to LDS ---
    #pragma unroll
    for (int u = 0; u < 4; ++u) {
        const int cidx = tid + 256 * u;
        const int n    = cidx >> 4;
        const int off  = (cidx & 15) * 8;
        const float* p = V + base + (size_t)n * (H * D) + off;
        float4 f0 = *(const float4*)p;
        float4 f1 = *(const float4*)(p + 4);
        unsigned int w[4];
        w[0] = pk2(f0.x, f0.y); w[1] = pk2(f0.z, f0.w);
        w[2] = pk2(f1.x, f1.y); w[3] = pk2(f1.z, f1.w);
        *(uint4*)&Vst[n * KSTR + off] = *(const uint4*)w;
    }
    __syncthreads();

    // --- transpose into Vout: dest col sigma holds source row k ---
    const int d  = tid >> 1;
    const int kh = (tid & 1) * 32;
    unsigned short tmp[32];
    #pragma unroll
    for (int m = 0; m < 32; ++m) {
        const int sig = kh + m;
        const int k = (sig & ~12) | ((sig & 4) << 1) | ((sig & 8) >> 1);
        tmp[m] = Vst[k * KSTR + d];
    }
    const int g = d >> 3, rho = d & 7;
    #pragma unroll
    for (int uu = 0; uu < 4; ++uu) {
        const int cc = (kh >> 3) + uu;
        *(uint4*)&Vout[g * 512 + (rho * 8 + (cc ^ rho)) * 8] = *(const uint4*)&tmp[uu * 8];
    }
    __syncthreads();

    // --- linear coalesced write of the finished V tile ---
    unsigned short* outV = Vtb + ((size_t)bh * 32 + t) * TILE;
    #pragma unroll
    for (int u = 0; u < 4; ++u) {
        const int dlin = u * 256 + tid;
        *(uint4*)(outV + dlin * 8) = *(const uint4*)&Vout[dlin * 8];
    }
}

__global__ __launch_bounds__(512, 2) void fa_fwd(
    const float* __restrict__ Q,
    const unsigned short* __restrict__ Kb,
    const unsigned short* __restrict__ Vtb,
    const int* __restrict__ causal_p,
    float* __restrict__ Op)
{
    __shared__ unsigned short Kl[3][TILE];   // 48 KB (merge scratch aliases this)
    __shared__ unsigned short Vl[3][TILE];   // 48 KB
    __shared__ float lbf[4][32];
    // ~97 KB -> 1 block/CU

    const int tid  = threadIdx.x;
    const int w    = tid >> 6;   // wave 0..7
    const int lane = tid & 63;
    const int ln   = lane & 31;
    const int half = lane >> 5;
    const int qw   = w & 3;      // q-group (32 rows)
    const int nt   = w >> 2;     // k-half of the 64-row KV tile

    // XCD-pinned remap (4 bh per XCD -> K/V workspace L2-resident).
    int bh, qp;
    if (gridDim.x == 8 && gridDim.y == 32) {
        const int lid = blockIdx.x + (blockIdx.y << 3);
        const int xcd = lid & 7;
        const int ii  = lid >> 3;             // 0..31
        bh = (xcd << 2) + (ii & 3);
        qp = ii >> 2;                         // 0..7
    } else {
        bh = blockIdx.y;
        qp = blockIdx.x;
    }
    const int b = bh >> 4;
    const int h = bh & 15;
    const int causal = *causal_p;
    const float cfold = 0.12751743f;  // (1/sqrt(D)) * log2(e), folded into Q

    const unsigned short* Ksrc = Kb  + (size_t)bh * (32 * TILE);
    const unsigned short* Vsrc = Vtb + (size_t)bh * (32 * TILE);
    const int sgk  = w * 2;           // this wave's 2 staging chunks (K and V)
    const int loff = lane * 8;        // shorts: lane*16B within a 1KB chunk

    // loop-invariant permuted read addressing
    const int kb   = (ln >> 3) * 1024 + (ln & 7) * 128;  // shorts (+nt*4096)
    const int krho = ln & 7;
    const int vg   = (ln >> 3) * 512;                    // shorts (+dt*2048)
    const int vrho = ln & 7;

    #pragma unroll 1
    for (int ph = 0; ph < 2; ++ph) {
        const int qblk  = ph ? (15 - qp) : qp;   // pair sums to 34 tiles
        const int q0    = qblk * BM;
        const int qrow0 = q0 + qw * 32;
        const int jmax  = causal ? ((q0 + BM - 1) >> 6) : (S / 64 - 1);  // >= 1

        // ---- prologue: stage tiles 0 and 1 ----
        #pragma unroll
        for (int c2 = 0; c2 < 2; ++c2) {
            gld16(Ksrc + (sgk + c2) * 512 + loff, &Kl[0][(sgk + c2) * 512]);
            gld16(Vsrc + (sgk + c2) * 512 + loff, &Vl[0][(sgk + c2) * 512]);
        }
        #pragma unroll
        for (int c2 = 0; c2 < 2; ++c2) {
            gld16(Ksrc + TILE + (sgk + c2) * 512 + loff, &Kl[1][(sgk + c2) * 512]);
            gld16(Vsrc + TILE + (sgk + c2) * 512 + loff, &Vl[1][(sgk + c2) * 512]);
        }

        // ---- Q fragments (B-operand; lane = q col), pre-scaled ----
        bf16x8 qf[8];
        {
            const size_t rowoff = ((size_t)(b * S + qrow0 + ln) * H + h) * D;
            #pragma unroll
            for (int c = 0; c < 8; ++c) {
                float4 f0 = *(const float4*)(Q + rowoff + c * 16 + half * 8);
                float4 f1 = *(const float4*)(Q + rowoff + c * 16 + half * 8 + 4);
                unsigned int t[4];
                t[0] = pk2(f0.x * cfold, f0.y * cfold);
                t[1] = pk2(f0.z * cfold, f0.w * cfold);
                t[2] = pk2(f1.x * cfold, f1.y * cfold);
                t[3] = pk2(f1.z * cfold, f1.w * cfold);
                qf[c] = *(const bf16x8*)t;
            }
        }

        f32x16 o[4];
        #pragma unroll
        for (int dt = 0; dt < 4; ++dt)
            #pragma unroll
            for (int r = 0; r < 16; ++r) o[dt][r] = 0.0f;
        float l = 0.0f;

        asm volatile("s_waitcnt vmcnt(0)" ::: "memory");   // tiles 0,1 landed
        __builtin_amdgcn_s_barrier();

        // ---- QK(0) ----
        f32x16 sacc_c, sacc_n;
        if ((!causal) || (nt * 32 <= qrow0 + 31)) {
            #pragma unroll
            for (int r = 0; r < 16; ++r) sacc_c[r] = 0.0f;
            const unsigned short* kl = &Kl[0][nt * 4096 + kb];
            #pragma unroll
            for (int c = 0; c < 8; ++c) {
                uint4 raw = *(const uint4*)(kl + (((2 * c + half) ^ krho) << 3));
                bf16x8 kf = *(const bf16x8*)&raw;
                sacc_c = __builtin_amdgcn_mfma_f32_32x32x16_bf16(kf, qf[c], sacc_c, 0, 0, 0);
            }
        }

        int cur = 0;  // j % 3
        #pragma unroll 1
        for (int j = 0; j <= jmax; ++j) {
            if (j > 0) {
                // drains stage(j+1), issued one FULL iteration ago
                asm volatile("s_waitcnt vmcnt(0)" ::: "memory");
                __builtin_amdgcn_s_barrier();
            }
            // ---- issue stage(j+2): buffer held tile j-1, all waves past
            // barrier j => done reading it (PV(j-1) completed pre-barrier) ----
            if (j + 2 <= jmax) {
                int nb = cur + 2; if (nb >= 3) nb -= 3;
                const unsigned short* ks = Ksrc + (size_t)(j + 2) * TILE;
                const unsigned short* vs = Vsrc + (size_t)(j + 2) * TILE;
                #pragma unroll
                for (int c2 = 0; c2 < 2; ++c2) {
                    gld16(ks + (sgk + c2) * 512 + loff, &Kl[nb][(sgk + c2) * 512]);
                    gld16(vs + (sgk + c2) * 512 + loff, &Vl[nb][(sgk + c2) * 512]);
                }
            }

            const bool actj = (!causal) || (j * 64 + nt * 32 <= qrow0 + 31);

            // ---- QK(j+1): independent of softmax(j) -> co-issues with it ----
            if (j < jmax && ((!causal) || ((j + 1) * 64 + nt * 32 <= qrow0 + 31))) {
                int nx = cur + 1; if (nx >= 3) nx -= 3;
                #pragma unroll
                for (int r = 0; r < 16; ++r) sacc_n[r] = 0.0f;
                const unsigned short* kl = &Kl[nx][nt * 4096 + kb];
                __builtin_amdgcn_s_setprio(1);
                #pragma unroll
                for (int c = 0; c < 8; ++c) {
                    uint4 raw = *(const uint4*)(kl + (((2 * c + half) ^ krho) << 3));
                    bf16x8 kf = *(const bf16x8*)&raw;
                    sacc_n = __builtin_amdgcn_mfma_f32_32x32x16_bf16(kf, qf[c], sacc_n, 0, 0, 0);
                }
                __builtin_amdgcn_s_setprio(0);
            }

            if (actj) {
                // ---- softmax numerator for tile j (no max-subtraction) ----
                float p[16];
                const int thr  = qrow0 + ln - j * 64;
                const bool full = (!causal) || (j * 64 + 63 <= qrow0);
                float l0 = 0.0f, l1 = 0.0f;
                #pragma unroll
                for (int r = 0; r < 16; ++r) {
                    float e = __builtin_amdgcn_exp2f(sacc_c[r]);
                    if (!full) {
                        const int kl_ = nt * 32 + (r & 3) + 8 * (r >> 2) + 4 * half;
                        if (kl_ > thr) e = 0.0f;
                    }
                    if (r & 1) l1 += e; else l0 += e;
                    p[r] = e;
                }
                l += l0 + l1;

                // ---- PV(j): pack P pairwise -> B-operand ----
                __builtin_amdgcn_s_setprio(1);
                #pragma unroll
                for (int win2 = 0; win2 < 2; ++win2) {
                    unsigned int pw[4];
                    #pragma unroll
                    for (int d2 = 0; d2 < 4; ++d2)
                        pw[d2] = pk2(p[win2 * 8 + 2 * d2], p[win2 * 8 + 2 * d2 + 1]);
                    bf16x8 pf = *(const bf16x8*)pw;
                    const int cc = (nt * 2 + win2) * 2 + half;
                    const int voff = ((vrho * 8) + (cc ^ vrho)) << 3;
                    #pragma unroll
                    for (int dt = 0; dt < 4; ++dt) {
                        uint4 raw = *(const uint4*)(&Vl[cur][dt * 2048 + vg + voff]);
                        bf16x8 vf = *(const bf16x8*)&raw;
                        o[dt] = __builtin_amdgcn_mfma_f32_32x32x16_bf16(vf, pf, o[dt], 0, 0, 0);
                    }
                }
                __builtin_amdgcn_s_setprio(0);
            }

            sacc_c = sacc_n;
            cur += 1; if (cur >= 3) cur -= 3;
        }

        __syncthreads();   // all QK/PV reads of Kl done before aliasing

        // ---- merge k-halves (scratch aliases Kl; stride MST=33 bank-clean) ----
        const float lp = l + __shfl_xor(l, 32);
        float* mb = reinterpret_cast<float*>(&Kl[0][0]) + qw * (64 * MST);
        if (w >= 4) {
            #pragma unroll
            for (int dt = 0; dt < 2; ++dt)
                #pragma unroll
                for (int r = 0; r < 16; ++r)
                    mb[lane * MST + dt * 16 + r] = o[dt][r];
            if (half == 0) lbf[qw][ln] = lp;
        }
        __syncthreads();
        float ltot = 1.0f;
        if (w < 4) {
            #pragma unroll
            for (int dt = 0; dt < 2; ++dt)
                #pragma unroll
                for (int r = 0; r < 16; ++r)
                    o[dt][r] += mb[lane * MST + dt * 16 + r];
            ltot = lp + lbf[qw][ln];
        }
        __syncthreads();
        if (w >= 4) {
            #pragma unroll
            for (int dt = 2; dt < 4; ++dt)
                #pragma unroll
                for (int r = 0; r < 16; ++r)
                    mb[lane * MST + (dt - 2) * 16 + r] = o[dt][r];
        }
        __syncthreads();
        if (w < 4) {
            #pragma unroll
            for (int dt = 2; dt < 4; ++dt)
                #pragma unroll
                for (int r = 0; r < 16; ++r)
                    o[dt][r] += mb[lane * MST + (dt - 2) * 16 + r];

            // ---- epilogue: direct register->global store (lane = q row) ----
            const float inv = 1.0f / ltot;
            float* op = Op + ((size_t)(b * S + qrow0 + ln) * H + h) * D;
            #pragma unroll
            for (int dt = 0; dt < 4; ++dt)
                #pragma unroll
                for (int rq = 0; rq < 4; ++rq) {
                    float4 st;
                    st.x = o[dt][rq * 4 + 0] * inv;
                    st.y = o[dt][rq * 4 + 1] * inv;
                    st.z = o[dt][rq * 4 + 2] * inv;
                    st.w = o[dt][rq * 4 + 3] * inv;
                    *(float4*)(op + dt * 32 + 8 * rq + 4 * half) = st;
                }
        }
        __syncthreads();   // protect Kl/Vl before next phase's staging
    }
}

extern "C" void kernel_launch(void* const* d_in, const int* in_sizes, int n_in,
                              void* d_out, int out_size, void* d_ws, size_t ws_size,
                              hipStream_t stream) {
    const int B = in_sizes[0] / (S * H * D);   // expect 2
    unsigned short* Kb  = (unsigned short*)d_ws;
    unsigned short* Vtb = Kb + (size_t)B * S * H * D;

    cvt_kv<<<dim3(S / 64, B * H), 256, 0, stream>>>(
        (const float*)d_in[1], (const float*)d_in[2], Kb, Vtb);
    fa_fwd<<<dim3(8, B * H), 512, 0, stream>>>(
        (const float*)d_in[0], Kb, Vtb, (const int*)d_in[3], (float*)d_out);
}

// Round 6
// 187.160 us; speedup vs baseline: 1.0332x; 1.0332x over previous
//
#include <hip/hip_runtime.h>

typedef short bf16x8 __attribute__((ext_vector_type(8)));
typedef float f32x16 __attribute__((ext_vector_type(16)));

constexpr int S = 2048;
constexpr int H = 16;
constexpr int D = 128;
constexpr int BM = 128;    // q rows per phase (4 q-groups x 32)
constexpr int TILE = 8192; // shorts per 64-row K/V tile (16 KB)
constexpr int KSTR = 136;  // prepass staging LDS stride (shorts)
constexpr int MST  = 33;   // merge scratch stride (floats)

// ---------------------------------------------------------------------------
// Workspace layouts (per (b,h), 32 tiles of 16KB), both REGISTER-direct:
//  K tile (chunk-major): [chunk 0..15][row 0..63] x 16B.  Fragment c of wave
//     (qw,nt): lane(ln,half) reads chunk 2c+half, row nt*32+ln ->
//     addr = c*1024 + half*512 + nt*256 + ln*8 (shorts): consecutive lanes =
//     consecutive 16B -> fully coalesced global_load_dwordx4 from L1/L2.
//  V tile (cc-major, sigma column order): [cc 0..7][d 0..127] x 16B, where
//     within 16B chunk cc, col slot m holds source k-row sigma-interleaved
//     (pair order matching pk2-packed P).  Fragment (win2,dt): lane(ln,half)
//     reads cc = nt*4+win2*2+half, d = dt*32+ln -> coalesced.
//
// fa_fwd v6: NO K/V LDS, NO DMA, NO barriers in the j-loop.  Each wave
// prefetches kr[8]/vr[8] one tile ahead (T14) and runs free; waves sync only
// at the per-phase merge.  The 4x q-group operand redundancy is served by L1;
// unique traffic streams from the XCD-pinned L2 (L3 backstop).
// q-pair schedule: exactly 34 KV-tiles per block, 256 blocks, 1 block/CU.
// ---------------------------------------------------------------------------

__device__ inline unsigned int pk2(float a, float b) {
    // pack 2 f32 -> 2 bf16 (RNE bit-trick; finite values only). low=a, high=b
    unsigned int ua = __builtin_bit_cast(unsigned int, a);
    unsigned int ub = __builtin_bit_cast(unsigned int, b);
    ua += 0x7fffu + ((ua >> 16) & 1u);
    ub += 0x7fffu + ((ub >> 16) & 1u);
    return (ua >> 16) | (ub & 0xffff0000u);
}

// ---- fused prepass: K -> chunk-major bf16 tiles; V -> transposed cc-major ----
__global__ __launch_bounds__(256) void cvt_kv(const float* __restrict__ K,
                                              const float* __restrict__ V,
                                              unsigned short* __restrict__ Kb,
                                              unsigned short* __restrict__ Vtb) {
    __shared__ unsigned short Kst[64 * KSTR];
    __shared__ unsigned short Vst[64 * KSTR];
    __shared__ unsigned short Vout[TILE];
    const int tid = threadIdx.x;
    const int t   = blockIdx.x;   // 64-row tile
    const int bh  = blockIdx.y;
    const int b = bh >> 4, h = bh & 15;
    const size_t base = ((size_t)(b * S + t * 64) * H + h) * D;

    // --- stage K and V rows into LDS (coalesced reads, cvt to bf16) ---
    #pragma unroll
    for (int u = 0; u < 4; ++u) {
        const int c   = tid + 256 * u;
        const int n   = c >> 4;
        const int off = (c & 15) * 8;
        const float* pk = K + base + (size_t)n * (H * D) + off;
        float4 f0 = *(const float4*)pk;
        float4 f1 = *(const float4*)(pk + 4);
        unsigned int w[4];
        w[0] = pk2(f0.x, f0.y); w[1] = pk2(f0.z, f0.w);
        w[2] = pk2(f1.x, f1.y); w[3] = pk2(f1.z, f1.w);
        *(uint4*)&Kst[n * KSTR + off] = *(const uint4*)w;
        const float* pv = V + base + (size_t)n * (H * D) + off;
        f0 = *(const float4*)pv;
        f1 = *(const float4*)(pv + 4);
        w[0] = pk2(f0.x, f0.y); w[1] = pk2(f0.z, f0.w);
        w[2] = pk2(f1.x, f1.y); w[3] = pk2(f1.z, f1.w);
        *(uint4*)&Vst[n * KSTR + off] = *(const uint4*)w;
    }
    __syncthreads();

    // --- K: chunk-major linear write ---
    unsigned short* outK = Kb + ((size_t)bh * 32 + t) * TILE;
    #pragma unroll
    for (int u = 0; u < 4; ++u) {
        const int s = u * 256 + tid;        // 16B slot = chunk*64 + row
        const int chunk = s >> 6;
        const int row   = s & 63;
        *(uint4*)(outK + s * 8) = *(const uint4*)&Kst[row * KSTR + chunk * 8];
    }

    // --- V: transpose (sigma pair-interleave) into cc-major Vout, write linear ---
    const int d  = tid >> 1;
    const int kh = (tid & 1) * 32;
    unsigned short tmp[32];
    #pragma unroll
    for (int m = 0; m < 32; ++m) {
        const int sig = kh + m;
        const int k = (sig & ~12) | ((sig & 4) << 1) | ((sig & 8) >> 1);
        tmp[m] = Vst[k * KSTR + d];
    }
    #pragma unroll
    for (int uu = 0; uu < 4; ++uu) {
        const int cc = (kh >> 3) + uu;
        *(uint4*)&Vout[(cc * 128 + d) * 8] = *(const uint4*)&tmp[uu * 8];
    }
    __syncthreads();
    unsigned short* outV = Vtb + ((size_t)bh * 32 + t) * TILE;
    #pragma unroll
    for (int u = 0; u < 4; ++u) {
        const int s = u * 256 + tid;
        *(uint4*)(outV + s * 8) = *(const uint4*)&Vout[s * 8];
    }
}

__global__ __launch_bounds__(512, 2) void fa_fwd(
    const float* __restrict__ Q,
    const unsigned short* __restrict__ Kb,
    const unsigned short* __restrict__ Vtb,
    const int* __restrict__ causal_p,
    float* __restrict__ Op)
{
    __shared__ float mbf[4][64 * MST];   // merge scratch (~33.8 KB)
    __shared__ float lbf[4][32];

    const int tid  = threadIdx.x;
    const int w    = tid >> 6;   // wave 0..7
    const int lane = tid & 63;
    const int ln   = lane & 31;
    const int half = lane >> 5;
    const int qw   = w & 3;      // q-group (32 rows)
    const int nt   = w >> 2;     // k-half of the 64-row KV tile

    // XCD-pinned remap (4 bh per XCD -> K/V workspace L2-resident).
    int bh, qp;
    if (gridDim.x == 8 && gridDim.y == 32) {
        const int lid = blockIdx.x + (blockIdx.y << 3);
        const int xcd = lid & 7;
        const int ii  = lid >> 3;             // 0..31
        bh = (xcd << 2) + (ii & 3);
        qp = ii >> 2;                         // 0..7
    } else {
        bh = blockIdx.y;
        qp = blockIdx.x;
    }
    const int b = bh >> 4;
    const int h = bh & 15;
    const int causal = *causal_p;
    const float cfold = 0.12751743f;  // (1/sqrt(D)) * log2(e), folded into Q

    const unsigned short* Kc = Kb  + (size_t)bh * (32 * TILE);
    const unsigned short* Vc = Vtb + (size_t)bh * (32 * TILE);
    // per-lane invariant offsets (shorts)
    const int koff  = half * 512 + nt * 256 + ln * 8;   // + c*1024 per fragment
    const int vkoff = (nt * 4 + half) * 1024 + ln * 8;  // + win2*2048 + dt*256

    #pragma unroll 1
    for (int ph = 0; ph < 2; ++ph) {
        const int qblk  = ph ? (15 - qp) : qp;   // pair sums to 34 tiles
        const int q0    = qblk * BM;
        const int qrow0 = q0 + qw * 32;
        const int jmax  = causal ? ((q0 + BM - 1) >> 6) : (S / 64 - 1);

        // ---- Q fragments (B-operand; lane = q col), pre-scaled ----
        bf16x8 qf[8];
        {
            const size_t rowoff = ((size_t)(b * S + qrow0 + ln) * H + h) * D;
            #pragma unroll
            for (int c = 0; c < 8; ++c) {
                float4 f0 = *(const float4*)(Q + rowoff + c * 16 + half * 8);
                float4 f1 = *(const float4*)(Q + rowoff + c * 16 + half * 8 + 4);
                unsigned int t[4];
                t[0] = pk2(f0.x * cfold, f0.y * cfold);
                t[1] = pk2(f0.z * cfold, f0.w * cfold);
                t[2] = pk2(f1.x * cfold, f1.y * cfold);
                t[3] = pk2(f1.z * cfold, f1.w * cfold);
                qf[c] = *(const bf16x8*)t;
            }
        }

        f32x16 o[4];
        #pragma unroll
        for (int dt = 0; dt < 4; ++dt)
            #pragma unroll
            for (int r = 0; r < 16; ++r) o[dt][r] = 0.0f;
        float l0 = 0.0f, l1 = 0.0f;

        // ---- register prefetch of tile 0 (wave-private; no barrier ever) ----
        uint4 kr[8], vr[8];
        if ((!causal) || (nt * 32 <= qrow0 + 31)) {
            #pragma unroll
            for (int c = 0; c < 8; ++c)
                kr[c] = *(const uint4*)(Kc + c * 1024 + koff);
            #pragma unroll
            for (int i = 0; i < 8; ++i)
                vr[i] = *(const uint4*)(Vc + (i >> 2) * 2048 + (i & 3) * 256 + vkoff);
        }

        #pragma unroll 1
        for (int j = 0; j <= jmax; ++j) {
            const bool aj = (!causal) || (j * 64 + nt * 32 <= qrow0 + 31);
            const bool an = (j < jmax) &&
                            ((!causal) || ((j + 1) * 64 + nt * 32 <= qrow0 + 31));

            // ---- S^T = K Q^T from registers ----
            f32x16 sacc;
            if (aj) {
                #pragma unroll
                for (int r = 0; r < 16; ++r) sacc[r] = 0.0f;
                __builtin_amdgcn_s_setprio(1);
                #pragma unroll
                for (int c = 0; c < 8; ++c) {
                    bf16x8 kf = *(const bf16x8*)&kr[c];
                    sacc = __builtin_amdgcn_mfma_f32_32x32x16_bf16(kf, qf[c], sacc, 0, 0, 0);
                }
                __builtin_amdgcn_s_setprio(0);
            }
            // ---- prefetch K(j+1) (kr consumed above; WAR-safe in-order) ----
            if (an) {
                const unsigned short* kt = Kc + (size_t)(j + 1) * TILE;
                #pragma unroll
                for (int c = 0; c < 8; ++c)
                    kr[c] = *(const uint4*)(kt + c * 1024 + koff);
            }

            if (aj) {
                // ---- fused softmax numerator + PV (P never materializes) ----
                const int thr  = qrow0 + ln - j * 64;
                const bool full = (!causal) || (j * 64 + 63 <= qrow0);
                __builtin_amdgcn_s_setprio(1);
                #pragma unroll
                for (int win2 = 0; win2 < 2; ++win2) {
                    unsigned int pw[4];
                    #pragma unroll
                    for (int d2 = 0; d2 < 4; ++d2) {
                        const int r0 = win2 * 8 + 2 * d2;
                        const int r1 = r0 + 1;
                        float e0 = __builtin_amdgcn_exp2f(sacc[r0]);
                        float e1 = __builtin_amdgcn_exp2f(sacc[r1]);
                        if (!full) {
                            const int k0 = nt * 32 + (r0 & 3) + 8 * (r0 >> 2) + 4 * half;
                            const int k1 = nt * 32 + (r1 & 3) + 8 * (r1 >> 2) + 4 * half;
                            if (k0 > thr) e0 = 0.0f;
                            if (k1 > thr) e1 = 0.0f;
                        }
                        l0 += e0; l1 += e1;
                        pw[d2] = pk2(e0, e1);
                    }
                    bf16x8 pf = *(const bf16x8*)pw;
                    #pragma unroll
                    for (int dt = 0; dt < 4; ++dt) {
                        bf16x8 vf = *(const bf16x8*)&vr[win2 * 4 + dt];
                        o[dt] = __builtin_amdgcn_mfma_f32_32x32x16_bf16(vf, pf, o[dt], 0, 0, 0);
                    }
                }
                __builtin_amdgcn_s_setprio(0);
            }
            // ---- prefetch V(j+1) (vr consumed by PV above) ----
            if (an) {
                const unsigned short* vt = Vc + (size_t)(j + 1) * TILE;
                #pragma unroll
                for (int i = 0; i < 8; ++i)
                    vr[i] = *(const uint4*)(vt + (i >> 2) * 2048 + (i & 3) * 256 + vkoff);
            }
        }

        // ---- merge k-halves (upper waves -> LDS, lower waves add) ----
        const float l = l0 + l1;
        const float lp = l + __shfl_xor(l, 32);
        float* mb = mbf[qw];
        if (w >= 4) {
            #pragma unroll
            for (int dt = 0; dt < 2; ++dt)
                #pragma unroll
                for (int r = 0; r < 16; ++r)
                    mb[lane * MST + dt * 16 + r] = o[dt][r];
            if (half == 0) lbf[qw][ln] = lp;
        }
        __syncthreads();
        float ltot = 1.0f;
        if (w < 4) {
            #pragma unroll
            for (int dt = 0; dt < 2; ++dt)
                #pragma unroll
                for (int r = 0; r < 16; ++r)
                    o[dt][r] += mb[lane * MST + dt * 16 + r];
            ltot = lp + lbf[qw][ln];
        }
        __syncthreads();
        if (w >= 4) {
            #pragma unroll
            for (int dt = 2; dt < 4; ++dt)
                #pragma unroll
                for (int r = 0; r < 16; ++r)
                    mb[lane * MST + (dt - 2) * 16 + r] = o[dt][r];
        }
        __syncthreads();
        if (w < 4) {
            #pragma unroll
            for (int dt = 2; dt < 4; ++dt)
                #pragma unroll
                for (int r = 0; r < 16; ++r)
                    o[dt][r] += mb[lane * MST + (dt - 2) * 16 + r];

            // ---- epilogue: direct register->global store (lane = q row) ----
            const float inv = 1.0f / ltot;
            float* op = Op + ((size_t)(b * S + qrow0 + ln) * H + h) * D;
            #pragma unroll
            for (int dt = 0; dt < 4; ++dt)
                #pragma unroll
                for (int rq = 0; rq < 4; ++rq) {
                    float4 st;
                    st.x = o[dt][rq * 4 + 0] * inv;
                    st.y = o[dt][rq * 4 + 1] * inv;
                    st.z = o[dt][rq * 4 + 2] * inv;
                    st.w = o[dt][rq * 4 + 3] * inv;
                    *(float4*)(op + dt * 32 + 8 * rq + 4 * half) = st;
                }
        }
        __syncthreads();   // merge scratch reuse across phases
    }
}

extern "C" void kernel_launch(void* const* d_in, const int* in_sizes, int n_in,
                              void* d_out, int out_size, void* d_ws, size_t ws_size,
                              hipStream_t stream) {
    const int B = in_sizes[0] / (S * H * D);   // expect 2
    unsigned short* Kb  = (unsigned short*)d_ws;
    unsigned short* Vtb = Kb + (size_t)B * S * H * D;

    cvt_kv<<<dim3(S / 64, B * H), 256, 0, stream>>>(
        (const float*)d_in[1], (const float*)d_in[2], Kb, Vtb);
    fa_fwd<<<dim3(8, B * H), 512, 0, stream>>>(
        (const float*)d_in[0], Kb, Vtb, (const int*)d_in[3], (float*)d_out);
}